// Round 9
// baseline (10611.150 us; speedup 1.0000x reference)
//
#include <hip/hip_runtime.h>
#include <cmath>

#define T_LEN 4096
#define HIDN  512
#define G4    2048
#define KTAG  20
#define EMB   300
#define EMBP  304
#define NEGV  (-10000.0f)
#define TAG_START 18
#define TAG_STOP  19
#define NW    16     // workgroups per direction
#define UPW   32     // hidden units per WG
#define CRF_CHUNK 64
#define NCHUNK 64
#define KC 16

// ---- workspace layout (float offsets) ----
#define OFF_XP     ((size_t)0)                               // 2*4096*2048
#define OFF_GEMB   (OFF_XP + (size_t)2*T_LEN*G4)             // 4096*304
#define OFF_HSEQ   (OFF_GEMB + (size_t)T_LEN*EMBP)           // 2*4096*512
#define OFF_FEATS  (OFF_HSEQ + (size_t)2*T_LEN*HIDN)         // 4096*20
#define OFF_HBUF   (OFF_FEATS + (size_t)T_LEN*KTAG)          // 2dir*16rep*2par*512 u64
#define OFF_CHUNKP (OFF_HBUF + (size_t)2*NW*2*HIDN*2)        // 64*400

typedef _Float16 h2 __attribute__((ext_vector_type(2)));

#if __has_builtin(__builtin_amdgcn_fdot2)
#define FDOT2(a, b, c) __builtin_amdgcn_fdot2((a), (b), (c), false)
#else
static __device__ __forceinline__ float FDOT2(h2 a, h2 b, float c) {
  return c + (float)a.x * (float)b.x + (float)a.y * (float)b.y;
}
#endif

#if __has_builtin(__builtin_amdgcn_cvt_pkrtz)
static __device__ __forceinline__ h2 CVTPK(float x, float y) {
  return __builtin_bit_cast(h2, __builtin_amdgcn_cvt_pkrtz(x, y));
}
#else
static __device__ __forceinline__ h2 CVTPK(float x, float y) {
  h2 r; r.x = (_Float16)x; r.y = (_Float16)y; return r;
}
#endif

#if __has_builtin(__builtin_amdgcn_rcpf)
#define FRCP(x) __builtin_amdgcn_rcpf(x)
#else
#define FRCP(x) (1.0f / (x))
#endif

#if __has_builtin(__builtin_amdgcn_update_dpp)
template <int C>
static __device__ __forceinline__ float dppadd(float x) {
  int y = __builtin_amdgcn_update_dpp(0, __float_as_int(x), C, 0xF, 0xF, true);
  return x + __int_as_float(y);
}
// sum over the 16-lane row via rotations 1,2,4,8 (all lanes get the total)
static __device__ __forceinline__ float red16(float x) {
  x = dppadd<0x121>(x);  // row_ror:1
  x = dppadd<0x122>(x);  // row_ror:2
  x = dppadd<0x124>(x);  // row_ror:4
  x = dppadd<0x128>(x);  // row_ror:8
  return x;
}
#else
static __device__ __forceinline__ float red16(float x) {
  x += __shfl_xor(x, 1); x += __shfl_xor(x, 2);
  x += __shfl_xor(x, 4); x += __shfl_xor(x, 8);
  return x;
}
#endif

static __device__ __forceinline__ float fsig(float x) {
  return FRCP(1.0f + __expf(-x));
}
static __device__ __forceinline__ float ftanh(float x) {
  x = fminf(15.0f, fmaxf(-15.0f, x));
  float e = __expf(-2.0f * x);
  return (1.0f - e) * FRCP(1.0f + e);
}

// ---------------- init: publish tagged fp32 h(0) into parity-0 of ALL replicas
// slot = (tag<<32) | float_bits(h).  Poison tag 0xAAAAAAAA from the 0xAA ws
// fill never matches a real tag in [0,4096], so parity-1 needs no init.
__global__ void init_state(const float* __restrict__ h0,
                           unsigned long long* __restrict__ slots) {
  int idx = blockIdx.x * 512 + threadIdx.x;  // 32*512 = 2dir*16rep*512unit
  int dir = idx >> 13;
  int rep = (idx >> 9) & 15;
  int unit = idx & 511;
  slots[((size_t)(dir * NW + rep) * 2 + 0) * HIDN + unit] =
      (unsigned long long)__float_as_uint(h0[dir * HIDN + unit]);  // tag 0
}

// ---------------- embedding gather into contiguous padded rows ----------------
__global__ void gather_emb(const int* __restrict__ sentence,
                           const float* __restrict__ embed,
                           float* __restrict__ gemb) {
  int t = blockIdx.x;
  int row = sentence[t];
  const float* src = embed + (size_t)row * EMB;
  float* dst = gemb + (size_t)t * EMBP;
  for (int k = threadIdx.x; k < EMBP; k += blockDim.x)
    dst[k] = (k < EMB) ? src[k] : 0.0f;
}

// ---------------- x-projection GEMM: xp[dir][s][r] = emb(row(s)) . W[r] + b ----
__global__ __launch_bounds__(256) void xproj_gemm(
    const float* __restrict__ gemb,
    const float* __restrict__ w_ih_f, const float* __restrict__ b_ih_f,
    const float* __restrict__ b_hh_f,
    const float* __restrict__ w_ih_b, const float* __restrict__ b_ih_b,
    const float* __restrict__ b_hh_b,
    float* __restrict__ xp) {
  int dir = blockIdx.z;
  const float* W  = dir ? w_ih_b : w_ih_f;
  const float* bi = dir ? b_ih_b : b_ih_f;
  const float* bh = dir ? b_hh_b : b_hh_f;
  int t0 = blockIdx.x * 64, r0 = blockIdx.y * 64;
  __shared__ float As[KC][68];
  __shared__ float Bs[KC][68];
  int tid = threadIdx.x;
  int tx = tid & 15, ty = tid >> 4;
  int lr = tid >> 2, lk4 = tid & 3;
  float acc[4][4] = {{0.f}};
  int s = t0 + lr;
  int ga = dir ? (T_LEN - 1 - s) : s;   // backward dir scans reversed sentence
  const float* arow = gemb + (size_t)ga * EMBP;
  const float* wrow = W + (size_t)(r0 + lr) * EMB;
  for (int k0 = 0; k0 < EMB; k0 += KC) {
    int kb = k0 + lk4 * 4;
    float4 av = *(const float4*)(arow + kb);  // gemb zero-padded to 304
    float4 bv;
    bv.x = (kb + 0 < EMB) ? wrow[kb + 0] : 0.0f;
    bv.y = (kb + 1 < EMB) ? wrow[kb + 1] : 0.0f;
    bv.z = (kb + 2 < EMB) ? wrow[kb + 2] : 0.0f;
    bv.w = (kb + 3 < EMB) ? wrow[kb + 3] : 0.0f;
    __syncthreads();
    As[lk4*4+0][lr] = av.x; As[lk4*4+1][lr] = av.y;
    As[lk4*4+2][lr] = av.z; As[lk4*4+3][lr] = av.w;
    Bs[lk4*4+0][lr] = bv.x; Bs[lk4*4+1][lr] = bv.y;
    Bs[lk4*4+2][lr] = bv.z; Bs[lk4*4+3][lr] = bv.w;
    __syncthreads();
#pragma unroll
    for (int kk = 0; kk < KC; ++kk) {
      float4 a = *(const float4*)&As[kk][ty * 4];
      float4 b = *(const float4*)&Bs[kk][tx * 4];
      acc[0][0]+=a.x*b.x; acc[0][1]+=a.x*b.y; acc[0][2]+=a.x*b.z; acc[0][3]+=a.x*b.w;
      acc[1][0]+=a.y*b.x; acc[1][1]+=a.y*b.y; acc[1][2]+=a.y*b.z; acc[1][3]+=a.y*b.w;
      acc[2][0]+=a.z*b.x; acc[2][1]+=a.z*b.y; acc[2][2]+=a.z*b.z; acc[2][3]+=a.z*b.w;
      acc[3][0]+=a.w*b.x; acc[3][1]+=a.w*b.y; acc[3][2]+=a.w*b.z; acc[3][3]+=a.w*b.w;
    }
  }
  int rr = r0 + tx * 4;
  float4 bi4 = *(const float4*)(bi + rr);
  float4 bh4 = *(const float4*)(bh + rr);
#pragma unroll
  for (int i = 0; i < 4; ++i) {
    int t = t0 + ty * 4 + i;
    float4 v = {acc[i][0] + bi4.x + bh4.x, acc[i][1] + bi4.y + bh4.y,
                acc[i][2] + bi4.z + bh4.z, acc[i][3] + bi4.w + bh4.w};
    *(float4*)(xp + ((size_t)dir * T_LEN + t) * G4 + rr) = v;
  }
}

// ---------------- LSTM recurrence ------------------------------------------
// r6 structure (best measured: 6.72 ms) with ONE change: per-consumer-WG slot
// REPLICATION. r6's FETCH_SIZE excess (~100 MB) showed the shared slot lines
// bouncing across all 8 XCDs every step (8 readers + 16 writer-WGs contending
// at the IF). Now each publisher stores its tagged value to 16 replicas (one
// per consumer WG, staggered order); each WG polls only its private replica,
// so poll lines are never shared across WGs -> local-TCC polls, single
// invalidate per line per step, no multi-reader IF contention. Publish path
// otherwise untouched; poll loop is the simple dependent load (r8 showed
// pipelined polls regress).
__global__ __launch_bounds__(512) void lstm_rec(
    const float* __restrict__ xp,
    const float* __restrict__ w_hh_f, const float* __restrict__ w_hh_b,
    const float* __restrict__ c0,
    float* __restrict__ hseq,
    unsigned long long* slots) {
  const int dir = blockIdx.x >> 4;
  const int w = blockIdx.x & 15;
  const int tid = threadIdx.x;
  const int u = tid >> 4;          // unit within WG [0,32)
  const int s = tid & 15;          // col-split: cols [s*32, s*32+32)
  const int unit_g = w * UPW + u;  // global unit [0,512)
  const float* Whh = dir ? w_hh_b : w_hh_f;
  h2 wreg[4][16];                  // packed f16 weights: [gate][col-pair]
#pragma unroll
  for (int g = 0; g < 4; ++g) {
    const float* wsrc = Whh + ((size_t)(g * HIDN + unit_g)) * HIDN + s * 32;
#pragma unroll
    for (int k = 0; k < 16; ++k)
      wreg[g][k] = CVTPK(wsrc[2 * k], wsrc[2 * k + 1]);
  }
  const bool pub = (s == 0);
  float c_own = pub ? c0[dir * HIDN + unit_g] : 0.0f;
  __shared__ float h_sh[2][16 * 36];  // fp32, chunk stride 36 -> 2-way (free)
  // hoisted per-step pointers
  const float* xq = xp + (size_t)dir * T_LEN * G4 + unit_g;
  // private replica for this WG: [dir*NW + w][parity][512]
  unsigned long long* slot_rd[2] = {
      slots + ((size_t)(dir * NW + w) * 2 + 0) * HIDN + tid,
      slots + ((size_t)(dir * NW + w) * 2 + 1) * HIDN + tid};
  // publish base for this dir (replica r at offset r*2*HIDN)
  unsigned long long* pub_base = slots + (size_t)(dir * NW) * 2 * HIDN + unit_g;
  float* hst = hseq + (size_t)dir * T_LEN * HIDN + unit_g;

  for (int t = 1; t <= T_LEN; ++t) {
    const int p = (t - 1) & 1;
    // prefetch this step's 4 xp gate values (latency hides under poll)
    float xv0 = 0.f, xv1 = 0.f, xv2 = 0.f, xv3 = 0.f;
    if (pub) {
      xv0 = xq[0]; xv1 = xq[HIDN]; xv2 = xq[2 * HIDN]; xv3 = xq[3 * HIDN];
    }
    xq += G4;
    // poll own slot in the WG-private replica (local XCD lines)
    unsigned long long v;
    do {
      v = __hip_atomic_load(slot_rd[p], __ATOMIC_RELAXED, __HIP_MEMORY_SCOPE_AGENT);
    } while ((unsigned)(v >> 32) != (unsigned)(t - 1));
    h_sh[p][(tid >> 5) * 36 + (tid & 31)] = __uint_as_float((unsigned)v);
    __syncthreads();
    // ---- matvec: read 32 fp32 h, pack to f16 pairs, 64 dot2 ----
    const float* hq = &h_sh[p][s * 36];
    h2 hh[16];
#pragma unroll
    for (int k = 0; k < 8; ++k) {
      float4 f = *(const float4*)(hq + k * 4);
      hh[2 * k]     = CVTPK(f.x, f.y);
      hh[2 * k + 1] = CVTPK(f.z, f.w);
    }
    float a0 = 0.f, a1 = 0.f, a2 = 0.f, a3 = 0.f;
#pragma unroll
    for (int k = 0; k < 16; ++k) {
      a0 = FDOT2(wreg[0][k], hh[k], a0);
      a1 = FDOT2(wreg[1][k], hh[k], a1);
      a2 = FDOT2(wreg[2][k], hh[k], a2);
      a3 = FDOT2(wreg[3][k], hh[k], a3);
    }
    // reduce over the 16 col-splits in the VALU pipe (DPP rotations)
    a0 = red16(a0); a1 = red16(a1); a2 = red16(a2); a3 = red16(a3);
    if (pub) {  // lane s==0 holds complete i,f,g,o for unit u
      float iS = fsig(a0 + xv0);
      float fS = fsig(a1 + xv1);
      float gT = ftanh(a2 + xv2);
      float oS = fsig(a3 + xv3);
      c_own = fS * c_own + iS * gT;
      float hv = oS * ftanh(c_own);
      unsigned long long pk =
          ((unsigned long long)(unsigned)t << 32) | __float_as_uint(hv);
      unsigned long long* pb = pub_base + (size_t)(t & 1) * HIDN;
      // fan out to all 16 consumer-WG replicas, staggered start at w+1
#pragma unroll
      for (int r = 0; r < NW; ++r) {
        int rw = (w + 1 + r) & (NW - 1);
        __hip_atomic_store(pb + (size_t)rw * 2 * HIDN, pk, __ATOMIC_RELAXED,
                           __HIP_MEMORY_SCOPE_AGENT);
      }
      hst[0] = hv;
    }
    hst += HIDN;
  }
}

// ---------------- feats: one wave per t, 20 dot-1024 reductions ---------------
__global__ __launch_bounds__(256) void feats_kernel(
    const float* __restrict__ hseq, const float* __restrict__ W_tag,
    const float* __restrict__ b_tag, float* __restrict__ feats) {
  int gw = (blockIdx.x * blockDim.x + threadIdx.x) >> 6;
  int lane = threadIdx.x & 63;
  if (gw >= T_LEN) return;
  const float* hf = hseq + (size_t)gw * HIDN;
  const float* hb = hseq + ((size_t)T_LEN + (T_LEN - 1 - gw)) * HIDN;
  float4 a0 = *(const float4*)(hf + lane * 8);
  float4 a1 = *(const float4*)(hf + lane * 8 + 4);
  float4 b0 = *(const float4*)(hb + lane * 8);
  float4 b1 = *(const float4*)(hb + lane * 8 + 4);
  for (int j = 0; j < KTAG; ++j) {
    const float* wr = W_tag + (size_t)j * (2 * HIDN) + lane * 8;
    float4 wa0 = *(const float4*)(wr);
    float4 wa1 = *(const float4*)(wr + 4);
    float4 wb0 = *(const float4*)(wr + HIDN);
    float4 wb1 = *(const float4*)(wr + HIDN + 4);
    float s = a0.x*wa0.x + a0.y*wa0.y + a0.z*wa0.z + a0.w*wa0.w
            + a1.x*wa1.x + a1.y*wa1.y + a1.z*wa1.z + a1.w*wa1.w
            + b0.x*wb0.x + b0.y*wb0.y + b0.z*wb0.z + b0.w*wb0.w
            + b1.x*wb1.x + b1.y*wb1.y + b1.z*wb1.z + b1.w*wb1.w;
#pragma unroll
    for (int off = 32; off; off >>= 1) s += __shfl_xor(s, off);
    if (lane == 0) feats[gw * KTAG + j] = s + b_tag[j];
  }
}

// ---------------- CRF: parallel chunk matrices in the (LSE,+) semiring -------
__global__ __launch_bounds__(512) void crf_chunks(
    const float* __restrict__ feats, const float* __restrict__ trans,
    float* __restrict__ chunkP) {
  __shared__ float Tr[KTAG * KTAG];
  __shared__ float P[KTAG * KTAG];
  __shared__ float fch[CRF_CHUNK * KTAG];
  int tid = threadIdx.x;
  int c = blockIdx.x;
  int t0 = c * CRF_CHUNK;
  if (tid < KTAG * KTAG) Tr[tid] = trans[tid];
  for (int i = tid; i < CRF_CHUNK * KTAG; i += blockDim.x)
    fch[i] = feats[t0 * KTAG + i];
  int j = tid / KTAG, i0 = tid % KTAG;
  __syncthreads();
  if (tid < KTAG * KTAG) P[tid] = Tr[tid] + fch[j];  // M_{t0}
  __syncthreads();
  for (int tt = 1; tt < CRF_CHUNK; ++tt) {           // P <- M_t (x) P
    float r = 0.0f;
    if (tid < KTAG * KTAG) {
      float v[KTAG], m = -1e30f;
#pragma unroll
      for (int i = 0; i < KTAG; ++i) {
        v[i] = Tr[j * KTAG + i] + P[i * KTAG + i0];
        m = fmaxf(m, v[i]);
      }
      float ssum = 0.0f;
#pragma unroll
      for (int i = 0; i < KTAG; ++i) ssum += __expf(v[i] - m);
      r = m + __logf(ssum) + fch[tt * KTAG + j];
    }
    __syncthreads();
    if (tid < KTAG * KTAG) P[tid] = r;
    __syncthreads();
  }
  if (tid < KTAG * KTAG) chunkP[c * KTAG * KTAG + tid] = P[tid];
}

// ---------------- final fold + gold score + output ---------------------------
__global__ __launch_bounds__(512) void crf_final(
    const float* __restrict__ chunkP, const float* __restrict__ feats,
    const float* __restrict__ trans, const int* __restrict__ tags,
    float* __restrict__ out) {
  __shared__ float red[512];
  __shared__ float alpha[KTAG];
  int tid = threadIdx.x;
  float g = 0.0f;
  for (int t = tid; t < T_LEN; t += 512) {
    int ct = tags[t];
    int pt = (t == 0) ? TAG_START : tags[t - 1];
    g += trans[ct * KTAG + pt] + feats[t * KTAG + ct];
  }
  if (tid == 0) g += trans[TAG_STOP * KTAG + tags[T_LEN - 1]];
  red[tid] = g;
  __syncthreads();
  for (int s = 256; s > 0; s >>= 1) {
    if (tid < s) red[tid] += red[tid + s];
    __syncthreads();
  }
  if (tid < KTAG) alpha[tid] = (tid == TAG_START) ? 0.0f : NEGV;
  __syncthreads();
  for (int c = 0; c < NCHUNK; ++c) {
    float r = 0.0f;
    if (tid < KTAG) {
      const float* Pc = chunkP + c * KTAG * KTAG + tid * KTAG;
      float v[KTAG], m = -1e30f;
#pragma unroll
      for (int i = 0; i < KTAG; ++i) {
        v[i] = Pc[i] + alpha[i];
        m = fmaxf(m, v[i]);
      }
      float ssum = 0.0f;
#pragma unroll
      for (int i = 0; i < KTAG; ++i) ssum += __expf(v[i] - m);
      r = m + __logf(ssum);
    }
    __syncthreads();
    if (tid < KTAG) alpha[tid] = r;
    __syncthreads();
  }
  if (tid == 0) {
    float v[KTAG], m = -1e30f;
#pragma unroll
    for (int i = 0; i < KTAG; ++i) {
      v[i] = alpha[i] + trans[TAG_STOP * KTAG + i];
      m = fmaxf(m, v[i]);
    }
    float ssum = 0.0f;
#pragma unroll
    for (int i = 0; i < KTAG; ++i) ssum += __expf(v[i] - m);
    out[0] = (m + __logf(ssum)) - red[0];
  }
}

extern "C" void kernel_launch(void* const* d_in, const int* in_sizes, int n_in,
                              void* d_out, int out_size, void* d_ws, size_t ws_size,
                              hipStream_t stream) {
  const int*   sentence = (const int*)d_in[0];
  const int*   tags     = (const int*)d_in[1];
  const float* embed    = (const float*)d_in[2];
  const float* w_ih_f   = (const float*)d_in[3];
  const float* w_hh_f   = (const float*)d_in[4];
  const float* b_ih_f   = (const float*)d_in[5];
  const float* b_hh_f   = (const float*)d_in[6];
  const float* w_ih_b   = (const float*)d_in[7];
  const float* w_hh_b   = (const float*)d_in[8];
  const float* b_ih_b   = (const float*)d_in[9];
  const float* b_hh_b   = (const float*)d_in[10];
  const float* h0       = (const float*)d_in[11];
  const float* c0       = (const float*)d_in[12];
  const float* W_tag    = (const float*)d_in[13];
  const float* b_tag    = (const float*)d_in[14];
  const float* trans    = (const float*)d_in[15];
  float* out = (float*)d_out;

  float* ws      = (float*)d_ws;
  float* xp      = ws + OFF_XP;
  float* gemb    = ws + OFF_GEMB;
  float* hseq    = ws + OFF_HSEQ;
  float* feats   = ws + OFF_FEATS;
  unsigned long long* slots = (unsigned long long*)(ws + OFF_HBUF);
  float* chunkP  = ws + OFF_CHUNKP;

  hipLaunchKernelGGL(init_state, dim3(32), dim3(512), 0, stream, h0, slots);
  hipLaunchKernelGGL(gather_emb, dim3(T_LEN), dim3(128), 0, stream,
                     sentence, embed, gemb);
  hipLaunchKernelGGL(xproj_gemm, dim3(64, 32, 2), dim3(256), 0, stream,
                     gemb, w_ih_f, b_ih_f, b_hh_f, w_ih_b, b_ih_b, b_hh_b, xp);
  hipLaunchKernelGGL(lstm_rec, dim3(32), dim3(512), 0, stream,
                     xp, w_hh_f, w_hh_b, c0, hseq, slots);
  hipLaunchKernelGGL(feats_kernel, dim3(1024), dim3(256), 0, stream,
                     hseq, W_tag, b_tag, feats);
  hipLaunchKernelGGL(crf_chunks, dim3(NCHUNK), dim3(512), 0, stream,
                     feats, trans, chunkP);
  hipLaunchKernelGGL(crf_final, dim3(1), dim3(512), 0, stream,
                     chunkP, feats, trans, tags, out);
}

// Round 10
// 6991.721 us; speedup vs baseline: 1.5177x; 1.5177x over previous
//
#include <hip/hip_runtime.h>
#include <cmath>

#define T_LEN 4096
#define HIDN  512
#define G4    2048
#define KTAG  20
#define EMB   300
#define EMBP  304
#define NEGV  (-10000.0f)
#define TAG_START 18
#define TAG_STOP  19
#define NW    16     // workgroups per direction
#define UPW   32     // hidden units per WG
#define CRF_CHUNK 64
#define NCHUNK 64
#define KC 16

// ---- workspace layout (float offsets) ----
#define OFF_XP     ((size_t)0)                               // 2*4096*2048
#define OFF_GEMB   (OFF_XP + (size_t)2*T_LEN*G4)             // 4096*304
#define OFF_HSEQ   (OFF_GEMB + (size_t)T_LEN*EMBP)           // 2*4096*512
#define OFF_FEATS  (OFF_HSEQ + (size_t)2*T_LEN*HIDN)         // 4096*20
#define OFF_HBUF   (OFF_FEATS + (size_t)T_LEN*KTAG)          // 2 parity * 2 dir * 512 u64
#define OFF_CHUNKP (OFF_HBUF + (size_t)2*2*HIDN*2)           // 64*400

typedef _Float16 h2 __attribute__((ext_vector_type(2)));

#if __has_builtin(__builtin_amdgcn_fdot2)
#define FDOT2(a, b, c) __builtin_amdgcn_fdot2((a), (b), (c), false)
#else
static __device__ __forceinline__ float FDOT2(h2 a, h2 b, float c) {
  return c + (float)a.x * (float)b.x + (float)a.y * (float)b.y;
}
#endif

#if __has_builtin(__builtin_amdgcn_cvt_pkrtz)
static __device__ __forceinline__ h2 CVTPK(float x, float y) {
  return __builtin_bit_cast(h2, __builtin_amdgcn_cvt_pkrtz(x, y));
}
#else
static __device__ __forceinline__ h2 CVTPK(float x, float y) {
  h2 r; r.x = (_Float16)x; r.y = (_Float16)y; return r;
}
#endif

#if __has_builtin(__builtin_amdgcn_rcpf)
#define FRCP(x) __builtin_amdgcn_rcpf(x)
#else
#define FRCP(x) (1.0f / (x))
#endif

#if __has_builtin(__builtin_amdgcn_update_dpp)
template <int C>
static __device__ __forceinline__ float dppadd(float x) {
  int y = __builtin_amdgcn_update_dpp(0, __float_as_int(x), C, 0xF, 0xF, true);
  return x + __int_as_float(y);
}
// sum over the 16-lane row via rotations 1,2,4,8 (all lanes get the total)
static __device__ __forceinline__ float red16(float x) {
  x = dppadd<0x121>(x);  // row_ror:1
  x = dppadd<0x122>(x);  // row_ror:2
  x = dppadd<0x124>(x);  // row_ror:4
  x = dppadd<0x128>(x);  // row_ror:8
  return x;
}
#else
static __device__ __forceinline__ float red16(float x) {
  x += __shfl_xor(x, 1); x += __shfl_xor(x, 2);
  x += __shfl_xor(x, 4); x += __shfl_xor(x, 8);
  return x;
}
#endif

static __device__ __forceinline__ float fsig(float x) {
  return FRCP(1.0f + __expf(-x));
}
static __device__ __forceinline__ float ftanh(float x) {
  x = fminf(15.0f, fmaxf(-15.0f, x));
  float e = __expf(-2.0f * x);
  return (1.0f - e) * FRCP(1.0f + e);
}

// ---------------- init: publish tagged fp32 h(0) into parity-0 slots ---------
// slot = (tag<<32) | float_bits(h).  Poison tag 0xAAAAAAAA from the 0xAA ws
// fill never matches a real tag in [0,4096], so parity-1 needs no init.
__global__ void init_state(const float* __restrict__ h0,
                           unsigned long long* __restrict__ slots) {
  int tid = threadIdx.x;  // 1024 = 2 dirs * 512 units
  slots[tid] = (unsigned long long)__float_as_uint(h0[tid]);  // tag 0
}

// ---------------- embedding gather into contiguous padded rows ----------------
__global__ void gather_emb(const int* __restrict__ sentence,
                           const float* __restrict__ embed,
                           float* __restrict__ gemb) {
  int t = blockIdx.x;
  int row = sentence[t];
  const float* src = embed + (size_t)row * EMB;
  float* dst = gemb + (size_t)t * EMBP;
  for (int k = threadIdx.x; k < EMBP; k += blockDim.x)
    dst[k] = (k < EMB) ? src[k] : 0.0f;
}

// ---------------- x-projection GEMM: xp[dir][s][r] = emb(row(s)) . W[r] + b ----
__global__ __launch_bounds__(256) void xproj_gemm(
    const float* __restrict__ gemb,
    const float* __restrict__ w_ih_f, const float* __restrict__ b_ih_f,
    const float* __restrict__ b_hh_f,
    const float* __restrict__ w_ih_b, const float* __restrict__ b_ih_b,
    const float* __restrict__ b_hh_b,
    float* __restrict__ xp) {
  int dir = blockIdx.z;
  const float* W  = dir ? w_ih_b : w_ih_f;
  const float* bi = dir ? b_ih_b : b_ih_f;
  const float* bh = dir ? b_hh_b : b_hh_f;
  int t0 = blockIdx.x * 64, r0 = blockIdx.y * 64;
  __shared__ float As[KC][68];
  __shared__ float Bs[KC][68];
  int tid = threadIdx.x;
  int tx = tid & 15, ty = tid >> 4;
  int lr = tid >> 2, lk4 = tid & 3;
  float acc[4][4] = {{0.f}};
  int s = t0 + lr;
  int ga = dir ? (T_LEN - 1 - s) : s;   // backward dir scans reversed sentence
  const float* arow = gemb + (size_t)ga * EMBP;
  const float* wrow = W + (size_t)(r0 + lr) * EMB;
  for (int k0 = 0; k0 < EMB; k0 += KC) {
    int kb = k0 + lk4 * 4;
    float4 av = *(const float4*)(arow + kb);  // gemb zero-padded to 304
    float4 bv;
    bv.x = (kb + 0 < EMB) ? wrow[kb + 0] : 0.0f;
    bv.y = (kb + 1 < EMB) ? wrow[kb + 1] : 0.0f;
    bv.z = (kb + 2 < EMB) ? wrow[kb + 2] : 0.0f;
    bv.w = (kb + 3 < EMB) ? wrow[kb + 3] : 0.0f;
    __syncthreads();
    As[lk4*4+0][lr] = av.x; As[lk4*4+1][lr] = av.y;
    As[lk4*4+2][lr] = av.z; As[lk4*4+3][lr] = av.w;
    Bs[lk4*4+0][lr] = bv.x; Bs[lk4*4+1][lr] = bv.y;
    Bs[lk4*4+2][lr] = bv.z; Bs[lk4*4+3][lr] = bv.w;
    __syncthreads();
#pragma unroll
    for (int kk = 0; kk < KC; ++kk) {
      float4 a = *(const float4*)&As[kk][ty * 4];
      float4 b = *(const float4*)&Bs[kk][tx * 4];
      acc[0][0]+=a.x*b.x; acc[0][1]+=a.x*b.y; acc[0][2]+=a.x*b.z; acc[0][3]+=a.x*b.w;
      acc[1][0]+=a.y*b.x; acc[1][1]+=a.y*b.y; acc[1][2]+=a.y*b.z; acc[1][3]+=a.y*b.w;
      acc[2][0]+=a.z*b.x; acc[2][1]+=a.z*b.y; acc[2][2]+=a.z*b.z; acc[2][3]+=a.z*b.w;
      acc[3][0]+=a.w*b.x; acc[3][1]+=a.w*b.y; acc[3][2]+=a.w*b.z; acc[3][3]+=a.w*b.w;
    }
  }
  int rr = r0 + tx * 4;
  float4 bi4 = *(const float4*)(bi + rr);
  float4 bh4 = *(const float4*)(bh + rr);
#pragma unroll
  for (int i = 0; i < 4; ++i) {
    int t = t0 + ty * 4 + i;
    float4 v = {acc[i][0] + bi4.x + bh4.x, acc[i][1] + bi4.y + bh4.y,
                acc[i][2] + bi4.z + bh4.z, acc[i][3] + bi4.w + bh4.w};
    *(float4*)(xp + ((size_t)dir * T_LEN + t) * G4 + rr) = v;
  }
}

// ---------------- LSTM recurrence ------------------------------------------
// r6 structure (best measured: 6.72 ms) with TWO off-structure tweaks:
// (1) publish via atomic_exchange (no sc0 return): RMW executes AT the
//     coherence point, so visibility starts at issue+transit instead of
//     whenever the write-combine buffer drains a relaxed store.
// (2) xp gate values prefetched ONE STEP AHEAD: cold-HBM xp loads get a full
//     step (~1.6us) to land, so an HBM latency spike can no longer stall a
//     WG's publish and propagate through the 32-WG sync max.
// Everything else (poll loop, LDS layout, barrier, matvec) byte-identical.
__global__ __launch_bounds__(512) void lstm_rec(
    const float* __restrict__ xp,
    const float* __restrict__ w_hh_f, const float* __restrict__ w_hh_b,
    const float* __restrict__ c0,
    float* __restrict__ hseq,
    unsigned long long* slots) {
  const int dir = blockIdx.x >> 4;
  const int w = blockIdx.x & 15;
  const int tid = threadIdx.x;
  const int u = tid >> 4;          // unit within WG [0,32)
  const int s = tid & 15;          // col-split: cols [s*32, s*32+32)
  const int unit_g = w * UPW + u;  // global unit [0,512)
  const float* Whh = dir ? w_hh_b : w_hh_f;
  h2 wreg[4][16];                  // packed f16 weights: [gate][col-pair]
#pragma unroll
  for (int g = 0; g < 4; ++g) {
    const float* wsrc = Whh + ((size_t)(g * HIDN + unit_g)) * HIDN + s * 32;
#pragma unroll
    for (int k = 0; k < 16; ++k)
      wreg[g][k] = CVTPK(wsrc[2 * k], wsrc[2 * k + 1]);
  }
  const bool pub = (s == 0);
  float c_own = pub ? c0[dir * HIDN + unit_g] : 0.0f;
  __shared__ float h_sh[2][16 * 36];  // fp32, chunk stride 36 -> 2-way (free)
  // hoisted per-step pointers
  const float* xq = xp + (size_t)dir * T_LEN * G4 + unit_g;
  unsigned long long* slot_rd[2] = {
      slots + ((size_t)0 * 2 + dir) * HIDN + tid,
      slots + ((size_t)1 * 2 + dir) * HIDN + tid};
  unsigned long long* slot_wr[2] = {
      slots + ((size_t)0 * 2 + dir) * HIDN + unit_g,
      slots + ((size_t)1 * 2 + dir) * HIDN + unit_g};
  float* hst = hseq + (size_t)dir * T_LEN * HIDN + unit_g;

  // prefetch step-1 xp gate values before the loop
  float xv0 = 0.f, xv1 = 0.f, xv2 = 0.f, xv3 = 0.f;
  if (pub) {
    xv0 = xq[0]; xv1 = xq[HIDN]; xv2 = xq[2 * HIDN]; xv3 = xq[3 * HIDN];
  }
  xq += G4;

  for (int t = 1; t <= T_LEN; ++t) {
    const int p = (t - 1) & 1;
    // issue NEXT step's xp loads now — a full step of latency budget
    float nx0 = 0.f, nx1 = 0.f, nx2 = 0.f, nx3 = 0.f;
    if (pub) {
      nx0 = xq[0]; nx1 = xq[HIDN]; nx2 = xq[2 * HIDN]; nx3 = xq[3 * HIDN];
    }
    xq += G4;
    // poll own slot: tag+payload arrive atomically in one 8B load
    unsigned long long v;
    do {
      v = __hip_atomic_load(slot_rd[p], __ATOMIC_RELAXED, __HIP_MEMORY_SCOPE_AGENT);
    } while ((unsigned)(v >> 32) != (unsigned)(t - 1));
    h_sh[p][(tid >> 5) * 36 + (tid & 31)] = __uint_as_float((unsigned)v);
    __syncthreads();
    // ---- matvec: read 32 fp32 h, pack to f16 pairs, 64 dot2 ----
    const float* hq = &h_sh[p][s * 36];
    h2 hh[16];
#pragma unroll
    for (int k = 0; k < 8; ++k) {
      float4 f = *(const float4*)(hq + k * 4);
      hh[2 * k]     = CVTPK(f.x, f.y);
      hh[2 * k + 1] = CVTPK(f.z, f.w);
    }
    float a0 = 0.f, a1 = 0.f, a2 = 0.f, a3 = 0.f;
#pragma unroll
    for (int k = 0; k < 16; ++k) {
      a0 = FDOT2(wreg[0][k], hh[k], a0);
      a1 = FDOT2(wreg[1][k], hh[k], a1);
      a2 = FDOT2(wreg[2][k], hh[k], a2);
      a3 = FDOT2(wreg[3][k], hh[k], a3);
    }
    // reduce over the 16 col-splits in the VALU pipe (DPP rotations)
    a0 = red16(a0); a1 = red16(a1); a2 = red16(a2); a3 = red16(a3);
    if (pub) {  // lane s==0 holds complete i,f,g,o for unit u
      float iS = fsig(a0 + xv0);
      float fS = fsig(a1 + xv1);
      float gT = ftanh(a2 + xv2);
      float oS = fsig(a3 + xv3);
      c_own = fS * c_own + iS * gT;
      float hv = oS * ftanh(c_own);
      unsigned long long pk =
          ((unsigned long long)(unsigned)t << 32) | __float_as_uint(hv);
      // RMW publish: executes at the coherence point (no lingering store)
      (void)__hip_atomic_exchange(slot_wr[t & 1], pk, __ATOMIC_RELAXED,
                                  __HIP_MEMORY_SCOPE_AGENT);
      hst[0] = hv;
    }
    hst += HIDN;
    xv0 = nx0; xv1 = nx1; xv2 = nx2; xv3 = nx3;
  }
}

// ---------------- feats: one wave per t, 20 dot-1024 reductions ---------------
__global__ __launch_bounds__(256) void feats_kernel(
    const float* __restrict__ hseq, const float* __restrict__ W_tag,
    const float* __restrict__ b_tag, float* __restrict__ feats) {
  int gw = (blockIdx.x * blockDim.x + threadIdx.x) >> 6;
  int lane = threadIdx.x & 63;
  if (gw >= T_LEN) return;
  const float* hf = hseq + (size_t)gw * HIDN;
  const float* hb = hseq + ((size_t)T_LEN + (T_LEN - 1 - gw)) * HIDN;
  float4 a0 = *(const float4*)(hf + lane * 8);
  float4 a1 = *(const float4*)(hf + lane * 8 + 4);
  float4 b0 = *(const float4*)(hb + lane * 8);
  float4 b1 = *(const float4*)(hb + lane * 8 + 4);
  for (int j = 0; j < KTAG; ++j) {
    const float* wr = W_tag + (size_t)j * (2 * HIDN) + lane * 8;
    float4 wa0 = *(const float4*)(wr);
    float4 wa1 = *(const float4*)(wr + 4);
    float4 wb0 = *(const float4*)(wr + HIDN);
    float4 wb1 = *(const float4*)(wr + HIDN + 4);
    float s = a0.x*wa0.x + a0.y*wa0.y + a0.z*wa0.z + a0.w*wa0.w
            + a1.x*wa1.x + a1.y*wa1.y + a1.z*wa1.z + a1.w*wa1.w
            + b0.x*wb0.x + b0.y*wb0.y + b0.z*wb0.z + b0.w*wb0.w
            + b1.x*wb1.x + b1.y*wb1.y + b1.z*wb1.z + b1.w*wb1.w;
#pragma unroll
    for (int off = 32; off; off >>= 1) s += __shfl_xor(s, off);
    if (lane == 0) feats[gw * KTAG + j] = s + b_tag[j];
  }
}

// ---------------- CRF: parallel chunk matrices in the (LSE,+) semiring -------
__global__ __launch_bounds__(512) void crf_chunks(
    const float* __restrict__ feats, const float* __restrict__ trans,
    float* __restrict__ chunkP) {
  __shared__ float Tr[KTAG * KTAG];
  __shared__ float P[KTAG * KTAG];
  __shared__ float fch[CRF_CHUNK * KTAG];
  int tid = threadIdx.x;
  int c = blockIdx.x;
  int t0 = c * CRF_CHUNK;
  if (tid < KTAG * KTAG) Tr[tid] = trans[tid];
  for (int i = tid; i < CRF_CHUNK * KTAG; i += blockDim.x)
    fch[i] = feats[t0 * KTAG + i];
  int j = tid / KTAG, i0 = tid % KTAG;
  __syncthreads();
  if (tid < KTAG * KTAG) P[tid] = Tr[tid] + fch[j];  // M_{t0}
  __syncthreads();
  for (int tt = 1; tt < CRF_CHUNK; ++tt) {           // P <- M_t (x) P
    float r = 0.0f;
    if (tid < KTAG * KTAG) {
      float v[KTAG], m = -1e30f;
#pragma unroll
      for (int i = 0; i < KTAG; ++i) {
        v[i] = Tr[j * KTAG + i] + P[i * KTAG + i0];
        m = fmaxf(m, v[i]);
      }
      float ssum = 0.0f;
#pragma unroll
      for (int i = 0; i < KTAG; ++i) ssum += __expf(v[i] - m);
      r = m + __logf(ssum) + fch[tt * KTAG + j];
    }
    __syncthreads();
    if (tid < KTAG * KTAG) P[tid] = r;
    __syncthreads();
  }
  if (tid < KTAG * KTAG) chunkP[c * KTAG * KTAG + tid] = P[tid];
}

// ---------------- final fold + gold score + output ---------------------------
__global__ __launch_bounds__(512) void crf_final(
    const float* __restrict__ chunkP, const float* __restrict__ feats,
    const float* __restrict__ trans, const int* __restrict__ tags,
    float* __restrict__ out) {
  __shared__ float red[512];
  __shared__ float alpha[KTAG];
  int tid = threadIdx.x;
  float g = 0.0f;
  for (int t = tid; t < T_LEN; t += 512) {
    int ct = tags[t];
    int pt = (t == 0) ? TAG_START : tags[t - 1];
    g += trans[ct * KTAG + pt] + feats[t * KTAG + ct];
  }
  if (tid == 0) g += trans[TAG_STOP * KTAG + tags[T_LEN - 1]];
  red[tid] = g;
  __syncthreads();
  for (int s = 256; s > 0; s >>= 1) {
    if (tid < s) red[tid] += red[tid + s];
    __syncthreads();
  }
  if (tid < KTAG) alpha[tid] = (tid == TAG_START) ? 0.0f : NEGV;
  __syncthreads();
  for (int c = 0; c < NCHUNK; ++c) {
    float r = 0.0f;
    if (tid < KTAG) {
      const float* Pc = chunkP + c * KTAG * KTAG + tid * KTAG;
      float v[KTAG], m = -1e30f;
#pragma unroll
      for (int i = 0; i < KTAG; ++i) {
        v[i] = Pc[i] + alpha[i];
        m = fmaxf(m, v[i]);
      }
      float ssum = 0.0f;
#pragma unroll
      for (int i = 0; i < KTAG; ++i) ssum += __expf(v[i] - m);
      r = m + __logf(ssum);
    }
    __syncthreads();
    if (tid < KTAG) alpha[tid] = r;
    __syncthreads();
  }
  if (tid == 0) {
    float v[KTAG], m = -1e30f;
#pragma unroll
    for (int i = 0; i < KTAG; ++i) {
      v[i] = alpha[i] + trans[TAG_STOP * KTAG + i];
      m = fmaxf(m, v[i]);
    }
    float ssum = 0.0f;
#pragma unroll
    for (int i = 0; i < KTAG; ++i) ssum += __expf(v[i] - m);
    out[0] = (m + __logf(ssum)) - red[0];
  }
}

extern "C" void kernel_launch(void* const* d_in, const int* in_sizes, int n_in,
                              void* d_out, int out_size, void* d_ws, size_t ws_size,
                              hipStream_t stream) {
  const int*   sentence = (const int*)d_in[0];
  const int*   tags     = (const int*)d_in[1];
  const float* embed    = (const float*)d_in[2];
  const float* w_ih_f   = (const float*)d_in[3];
  const float* w_hh_f   = (const float*)d_in[4];
  const float* b_ih_f   = (const float*)d_in[5];
  const float* b_hh_f   = (const float*)d_in[6];
  const float* w_ih_b   = (const float*)d_in[7];
  const float* w_hh_b   = (const float*)d_in[8];
  const float* b_ih_b   = (const float*)d_in[9];
  const float* b_hh_b   = (const float*)d_in[10];
  const float* h0       = (const float*)d_in[11];
  const float* c0       = (const float*)d_in[12];
  const float* W_tag    = (const float*)d_in[13];
  const float* b_tag    = (const float*)d_in[14];
  const float* trans    = (const float*)d_in[15];
  float* out = (float*)d_out;

  float* ws      = (float*)d_ws;
  float* xp      = ws + OFF_XP;
  float* gemb    = ws + OFF_GEMB;
  float* hseq    = ws + OFF_HSEQ;
  float* feats   = ws + OFF_FEATS;
  unsigned long long* slots = (unsigned long long*)(ws + OFF_HBUF);
  float* chunkP  = ws + OFF_CHUNKP;

  hipLaunchKernelGGL(init_state, dim3(1), dim3(1024), 0, stream, h0, slots);
  hipLaunchKernelGGL(gather_emb, dim3(T_LEN), dim3(128), 0, stream,
                     sentence, embed, gemb);
  hipLaunchKernelGGL(xproj_gemm, dim3(64, 32, 2), dim3(256), 0, stream,
                     gemb, w_ih_f, b_ih_f, b_hh_f, w_ih_b, b_ih_b, b_hh_b, xp);
  hipLaunchKernelGGL(lstm_rec, dim3(32), dim3(512), 0, stream,
                     xp, w_hh_f, w_hh_b, c0, hseq, slots);
  hipLaunchKernelGGL(feats_kernel, dim3(1024), dim3(256), 0, stream,
                     hseq, W_tag, b_tag, feats);
  hipLaunchKernelGGL(crf_chunks, dim3(NCHUNK), dim3(512), 0, stream,
                     feats, trans, chunkP);
  hipLaunchKernelGGL(crf_final, dim3(1), dim3(512), 0, stream,
                     chunkP, feats, trans, tags, out);
}